// Round 4
// baseline (123.519 us; speedup 1.0000x reference)
//
#include <hip/hip_runtime.h>
#include <hip/hip_bf16.h>

// B=32, T=4096, F=16, L=2047, n=8192, 256 output freqs.
// Math: s[b,t] = sum_f x[b,t,f]; r[b,tau] = sum_t s[t]*s[t+tau] (tau=0..2048)
// G[b,m] = (A[m]/16384) * exp(-2*pi*i*2047*m/4096),
// A[m] = r[0] + 2*sum_{j=1}^{2047} r[j]*cos(2*pi*m*j/4096) + (-1)^m r[2048].
// Output layout (verified R3): PLANAR — Re at [b*256+m], Im at [8192+b*256+m].

#define B_DIM 32
#define T_DIM 4096
#define NLAG 2049
#define NCHUNK 32
#define TS (T_DIM / NCHUNK)            // 128
#define THETA 1.5339807878856412e-03f  // 2*pi/4096

// LDS swizzle: +4 floats pad every 32 floats. Preserves 16B alignment and
// intra-float4 contiguity for all l%4==0 vector accesses; spreads the
// stride-8-floats/lane window reads evenly over all 32 banks.
#define SW(l) ((l) + (((l) >> 5) << 2))
#define LS_PHYS 4616                   // SW(4103)=4615 max touched

// ---------------- K1: s[b,t] = sum_f x[b,t,f]; also zero r ----------------
__global__ __launch_bounds__(256) void ksum(const float* __restrict__ x,
                                            float* __restrict__ s,
                                            float* __restrict__ r) {
    int i = blockIdx.x * 256 + threadIdx.x;          // 0..131071 = b*4096+t
    const float4* xv = (const float4*)(x + (size_t)i * 16);
    float4 a = xv[0], b = xv[1], c = xv[2], d = xv[3];
    s[i] = ((a.x + a.y) + (a.z + a.w)) + ((b.x + b.y) + (b.z + b.w)) +
           ((c.x + c.y) + (c.z + c.w)) + ((d.x + d.y) + (d.z + d.w));
    if (i < B_DIM * NLAG) r[i] = 0.0f;               // zero accumulator (ws is poisoned)
}

// ---------------- K2: register-tiled autocorrelation ----------------
// grid (32, NCHUNK); thread owns 8 contiguous lags tau0..tau0+7 over t-chunk
// [q*TS, q*TS+TS) via 12-wide sliding register window. Values verified in R1/R2.
__global__ __launch_bounds__(256) void kautoc(const float* __restrict__ s,
                                              float* __restrict__ r) {
    __shared__ __align__(16) float ls[LS_PHYS];
    int b = blockIdx.x;
    int q = blockIdx.y;
    const float4* sb4 = (const float4*)(s + (size_t)b * T_DIM);
    for (int idx = threadIdx.x; idx < 1026; idx += 256) {   // logical 0..4103
        int l = idx * 4;
        float4 v = make_float4(0.f, 0.f, 0.f, 0.f);
        if (l < T_DIM) v = sb4[idx];
        *(float4*)&ls[SW(l)] = v;                    // zero-padded tail -> clip-free
    }
    __syncthreads();

    int tau0 = threadIdx.x * 8;                      // 0..2040
    int t0 = q * TS;
    int tmax = T_DIM - tau0;
    if (tmax > t0 + TS) tmax = t0 + TS;

    if (t0 < tmax) {
        float acc[8] = {0.f, 0.f, 0.f, 0.f, 0.f, 0.f, 0.f, 0.f};
        float w[12];
        {
            int l0 = t0 + tau0;                      // multiple of 8
            float4 w0 = *(const float4*)&ls[SW(l0)];
            float4 w1 = *(const float4*)&ls[SW(l0 + 4)];
            w[0] = w0.x; w[1] = w0.y; w[2] = w0.z; w[3] = w0.w;
            w[4] = w1.x; w[5] = w1.y; w[6] = w1.z; w[7] = w1.w;
        }
        for (int t = t0; t + 4 <= tmax; t += 4) {    // TS%4==0 -> no tail
            int ln = t + tau0 + 8;                   // multiple of 4
            float4 nw = *(const float4*)&ls[SW(ln)];
            w[8] = nw.x; w[9] = nw.y; w[10] = nw.z; w[11] = nw.w;
            float4 av = *(const float4*)&ls[SW(t)];  // uniform -> broadcast
            float as[4] = {av.x, av.y, av.z, av.w};
            #pragma unroll
            for (int s2 = 0; s2 < 4; ++s2) {
                #pragma unroll
                for (int u = 0; u < 8; ++u)
                    acc[u] = fmaf(as[s2], w[s2 + u], acc[u]);
            }
            #pragma unroll
            for (int k = 0; k < 8; ++k) w[k] = w[k + 4];
        }
        #pragma unroll
        for (int u = 0; u < 8; ++u)
            atomicAdd(&r[(size_t)b * NLAG + tau0 + u], acc[u]);
    }

    // lag 2048: wave 3 (tids 192..255) strided over this chunk's t-range
    if (threadIdx.x >= 192 && t0 < 2048) {
        float a2 = 0.f;
        int tend = t0 + TS;                          // t0 <= 1920 -> tend <= 2048
        if (tend > 2048) tend = 2048;
        for (int t = t0 + (threadIdx.x - 192); t < tend; t += 64)
            a2 += ls[SW(t)] * ls[SW(t + 2048)];
        for (int off = 32; off; off >>= 1) a2 += __shfl_down(a2, off, 64);
        if (threadIdx.x == 192) atomicAdd(&r[(size_t)b * NLAG + 2048], a2);
    }
}

// ---------------- K3: one wave per (b,m), shuffle reduce ----------------
__global__ __launch_bounds__(64) void kdft(const float* __restrict__ r,
                                           float* __restrict__ out) {
    int b = blockIdx.x;
    int m = blockIdx.y;
    int lane = threadIdx.x;                          // 0..63
    const float* rb = r + (size_t)b * NLAG;
    float part = 0.0f;
    #pragma unroll 4
    for (int k = 0; k < 32; ++k) {                   // j = 0..2047
        int j = lane + (k << 6);
        int p = (m * j) & 4095;                      // exact integer phase
        part = fmaf(rb[j], __cosf((float)p * THETA), part);
    }
    for (int off = 32; off; off >>= 1) part += __shfl_down(part, off, 64);
    if (lane == 0) {
        // part = sum_{j=0}^{2047} r[j]cos; A = 2*part - r[0] + (-1)^m r[2048]
        float A = 2.0f * part - rb[0] + ((m & 1) ? -rb[2048] : rb[2048]);
        int qp = (2047 * m) & 4095;
        float ang = (float)qp * THETA;
        float g = A * (1.0f / 16384.0f);             // 1/(256 pairs)/sqrt(4096)
        out[(size_t)b * 256 + m] = g * cosf(ang);
        out[8192 + (size_t)b * 256 + m] = -g * sinf(ang);
    }
}

extern "C" void kernel_launch(void* const* d_in, const int* in_sizes, int n_in,
                              void* d_out, int out_size, void* d_ws, size_t ws_size,
                              hipStream_t stream) {
    const float* x = (const float*)d_in[0];
    float* out = (float*)d_out;
    float* s = (float*)d_ws;                          // 32*4096 floats
    float* r = s + B_DIM * T_DIM;                     // 32*2049 floats
    ksum<<<dim3(512), dim3(256), 0, stream>>>(x, s, r);
    kautoc<<<dim3(B_DIM, NCHUNK), dim3(256), 0, stream>>>(s, r);
    kdft<<<dim3(B_DIM, 256), dim3(64), 0, stream>>>(r, out);
}

// Round 5
// 94.109 us; speedup vs baseline: 1.3125x; 1.3125x over previous
//
#include <hip/hip_runtime.h>
#include <hip/hip_bf16.h>

// B=32, T=4096, F=16, L=2047, n=8192, 256 output freqs.
// Math: s[b,t] = sum_f x[b,t,f]; r[b,tau] = sum_t s[t]*s[t+tau] (tau=0..2048)
// G[b,m] = (A[m]/16384) * exp(-2*pi*i*2047*m/4096),
// A[m] = r[0] + 2*sum_{j=1}^{2047} r[j]*cos(2*pi*m*j/4096) + (-1)^m r[2048].
// Output layout (verified R3): PLANAR — Re at [b*256+m], Im at [8192+b*256+m].
// R5: atomics removed (R4: 2M device atomics -> 50MB HBM write-through, 64us).
//     Each chunk-block writes private partials; small reduce kernel sums them.

#define B_DIM 32
#define T_DIM 4096
#define NLAG 2049
#define NCHUNK 32
#define TS (T_DIM / NCHUNK)            // 128
#define PSTRIDE 2052                   // partial row stride (16B-aligned: 2052*4=8208)
#define THETA 1.5339807878856412e-03f  // 2*pi/4096

// LDS swizzle: +4 floats pad every 32 floats. Preserves 16B alignment and
// intra-float4 contiguity for all l%4==0 accesses; spreads stride-8 window reads.
#define SW(l) ((l) + (((l) >> 5) << 2))
#define LS_PHYS 4616

// ---------------- K1: s[b,t] = sum_f x[b,t,f] ----------------
__global__ __launch_bounds__(256) void ksum(const float* __restrict__ x,
                                            float* __restrict__ s) {
    int i = blockIdx.x * 256 + threadIdx.x;          // 0..131071 = b*4096+t
    const float4* xv = (const float4*)(x + (size_t)i * 16);
    float4 a = xv[0], b = xv[1], c = xv[2], d = xv[3];
    s[i] = ((a.x + a.y) + (a.z + a.w)) + ((b.x + b.y) + (b.z + b.w)) +
           ((c.x + c.y) + (c.z + c.w)) + ((d.x + d.y) + (d.z + d.w));
}

// ---------------- K2: register-tiled autocorr, private partials ----------------
// grid (32, NCHUNK); thread owns 8 contiguous lags tau0..tau0+7 over t-chunk
// [q*TS, q*TS+TS) via 12-wide sliding register window (values verified R1/R2).
// No atomics: block (b,q) writes part[(b*NCHUNK+q)*PSTRIDE + tau].
__global__ __launch_bounds__(256) void kautoc(const float* __restrict__ s,
                                              float* __restrict__ part) {
    __shared__ __align__(16) float ls[LS_PHYS];
    int b = blockIdx.x;
    int q = blockIdx.y;
    const float4* sb4 = (const float4*)(s + (size_t)b * T_DIM);
    for (int idx = threadIdx.x; idx < 1026; idx += 256) {   // logical 0..4103
        int l = idx * 4;
        float4 v = make_float4(0.f, 0.f, 0.f, 0.f);
        if (l < T_DIM) v = sb4[idx];
        *(float4*)&ls[SW(l)] = v;                    // zero-padded tail -> clip-free
    }
    __syncthreads();

    float* pr = part + ((size_t)b * NCHUNK + q) * PSTRIDE;

    int tau0 = threadIdx.x * 8;                      // 0..2040
    int t0 = q * TS;
    int tmax = T_DIM - tau0;
    if (tmax > t0 + TS) tmax = t0 + TS;

    float acc[8] = {0.f, 0.f, 0.f, 0.f, 0.f, 0.f, 0.f, 0.f};
    if (t0 < tmax) {
        float w[12];
        {
            int l0 = t0 + tau0;                      // multiple of 8
            float4 w0 = *(const float4*)&ls[SW(l0)];
            float4 w1 = *(const float4*)&ls[SW(l0 + 4)];
            w[0] = w0.x; w[1] = w0.y; w[2] = w0.z; w[3] = w0.w;
            w[4] = w1.x; w[5] = w1.y; w[6] = w1.z; w[7] = w1.w;
        }
        for (int t = t0; t + 4 <= tmax; t += 4) {    // TS%4==0 -> no tail
            int ln = t + tau0 + 8;                   // multiple of 4
            float4 nw = *(const float4*)&ls[SW(ln)];
            w[8] = nw.x; w[9] = nw.y; w[10] = nw.z; w[11] = nw.w;
            float4 av = *(const float4*)&ls[SW(t)];  // wave-uniform -> broadcast
            float as[4] = {av.x, av.y, av.z, av.w};
            #pragma unroll
            for (int s2 = 0; s2 < 4; ++s2) {
                #pragma unroll
                for (int u = 0; u < 8; ++u)
                    acc[u] = fmaf(as[s2], w[s2 + u], acc[u]);
            }
            #pragma unroll
            for (int k = 0; k < 8; ++k) w[k] = w[k + 4];
        }
    }
    // coalesced private store (always: zeros where no work)
    *(float4*)&pr[tau0]     = make_float4(acc[0], acc[1], acc[2], acc[3]);
    *(float4*)&pr[tau0 + 4] = make_float4(acc[4], acc[5], acc[6], acc[7]);

    // lag 2048: wave 3 (tids 192..255) strided over this chunk's t-range
    if (threadIdx.x >= 192) {
        float a2 = 0.f;
        if (t0 < 2048) {
            int tend = t0 + TS;                      // t0 <= 1920 -> tend <= 2048
            if (tend > 2048) tend = 2048;
            for (int t = t0 + (threadIdx.x - 192); t < tend; t += 64)
                a2 += ls[SW(t)] * ls[SW(t + 2048)];
        }
        for (int off = 32; off; off >>= 1) a2 += __shfl_down(a2, off, 64);
        if (threadIdx.x == 192) pr[2048] = a2;
    }
}

// ---------------- K2b: r[b,tau] = sum_q part[b][q][tau] ----------------
// grid (32); block b: threads stride over tau, coalesced reads per q.
__global__ __launch_bounds__(256) void kreduce(const float* __restrict__ part,
                                               float* __restrict__ r) {
    int b = blockIdx.x;
    const float* pb = part + (size_t)b * NCHUNK * PSTRIDE;
    for (int tau = threadIdx.x; tau < NLAG; tau += 256) {
        float acc = 0.f;
        #pragma unroll 8
        for (int q = 0; q < NCHUNK; ++q)
            acc += pb[(size_t)q * PSTRIDE + tau];
        r[(size_t)b * NLAG + tau] = acc;
    }
}

// ---------------- K3: one wave per (b,m), shuffle reduce ----------------
__global__ __launch_bounds__(64) void kdft(const float* __restrict__ r,
                                           float* __restrict__ out) {
    int b = blockIdx.x;
    int m = blockIdx.y;
    int lane = threadIdx.x;                          // 0..63
    const float* rb = r + (size_t)b * NLAG;
    float part = 0.0f;
    #pragma unroll 4
    for (int k = 0; k < 32; ++k) {                   // j = 0..2047
        int j = lane + (k << 6);
        int p = (m * j) & 4095;                      // exact integer phase
        part = fmaf(rb[j], __cosf((float)p * THETA), part);
    }
    for (int off = 32; off; off >>= 1) part += __shfl_down(part, off, 64);
    if (lane == 0) {
        // part = sum_{j=0}^{2047} r[j]cos; A = 2*part - r[0] + (-1)^m r[2048]
        float A = 2.0f * part - rb[0] + ((m & 1) ? -rb[2048] : rb[2048]);
        int qp = (2047 * m) & 4095;
        float ang = (float)qp * THETA;
        float g = A * (1.0f / 16384.0f);             // 1/(256 pairs)/sqrt(4096)
        out[(size_t)b * 256 + m] = g * cosf(ang);
        out[8192 + (size_t)b * 256 + m] = -g * sinf(ang);
    }
}

extern "C" void kernel_launch(void* const* d_in, const int* in_sizes, int n_in,
                              void* d_out, int out_size, void* d_ws, size_t ws_size,
                              hipStream_t stream) {
    const float* x = (const float*)d_in[0];
    float* out = (float*)d_out;
    float* s = (float*)d_ws;                          // 32*4096 floats (512 KB)
    float* r = s + B_DIM * T_DIM;                     // 32*2049 floats (262 KB)
    float* part = r + B_DIM * NLAG;                   // 32*32*2052 floats (8.4 MB)
    ksum<<<dim3(512), dim3(256), 0, stream>>>(x, s);
    kautoc<<<dim3(B_DIM, NCHUNK), dim3(256), 0, stream>>>(s, part);
    kreduce<<<dim3(B_DIM), dim3(256), 0, stream>>>(part, r);
    kdft<<<dim3(B_DIM, 256), dim3(64), 0, stream>>>(r, out);
}

// Round 6
// 84.074 us; speedup vs baseline: 1.4692x; 1.1194x over previous
//
#include <hip/hip_runtime.h>
#include <hip/hip_bf16.h>

// B=32, T=4096, F=16, L=2047, n=8192, 256 output freqs.
// Math: s[b,t] = sum_f x[b,t,f]; r[b,tau] = sum_t s[t]*s[t+tau] (tau=0..2048)
// G[b,m] = (A[m]/16384) * exp(-2*pi*i*2047*m/4096),
// A[m] = r[0] + 2*sum_{j=1}^{2047} r[j]*cos(2*pi*m*j/4096) + (-1)^m r[2048].
// Output layout (verified R3): PLANAR — Re at [b*256+m], Im at [8192+b*256+m].
// R5: atomics -> private partials + reduce (94us). R6: 8-wide unroll, NCHUNK=16,
//     LDS-staged kdft (L2 traffic 67MB -> 4.2MB).

#define B_DIM 32
#define T_DIM 4096
#define NLAG 2049
#define NCHUNK 16
#define TS (T_DIM / NCHUNK)            // 256
#define PSTRIDE 2052                   // partial row stride (16B-aligned)
#define THETA 1.5339807878856412e-03f  // 2*pi/4096

// LDS swizzle: +4 floats pad every 32. Preserves 16B alignment/contiguity for
// l%4==0 accesses; spreads stride-8-floats/lane window reads over all banks.
#define SW(l) ((l) + (((l) >> 5) << 2))
#define LS_PHYS 4616

// ---------------- K1: s[b,t] = sum_f x[b,t,f] ----------------
__global__ __launch_bounds__(256) void ksum(const float* __restrict__ x,
                                            float* __restrict__ s) {
    int i = blockIdx.x * 256 + threadIdx.x;          // 0..131071 = b*4096+t
    const float4* xv = (const float4*)(x + (size_t)i * 16);
    float4 a = xv[0], b = xv[1], c = xv[2], d = xv[3];
    s[i] = ((a.x + a.y) + (a.z + a.w)) + ((b.x + b.y) + (b.z + b.w)) +
           ((c.x + c.y) + (c.z + c.w)) + ((d.x + d.y) + (d.z + d.w));
}

// ---------------- K2: register-tiled autocorr, private partials ----------------
// grid (32, NCHUNK); thread owns 8 contiguous lags tau0..tau0+7 over t-chunk
// [q*TS, q*TS+TS) via 16-wide sliding register window, 8 t's per iteration.
__global__ __launch_bounds__(256) void kautoc(const float* __restrict__ s,
                                              float* __restrict__ part) {
    __shared__ __align__(16) float ls[LS_PHYS];
    int b = blockIdx.x;
    int q = blockIdx.y;
    const float4* sb4 = (const float4*)(s + (size_t)b * T_DIM);
    for (int idx = threadIdx.x; idx < 1026; idx += 256) {   // logical 0..4103
        int l = idx * 4;
        float4 v = make_float4(0.f, 0.f, 0.f, 0.f);
        if (l < T_DIM) v = sb4[idx];
        *(float4*)&ls[SW(l)] = v;                    // zero-padded tail -> clip-free
    }
    __syncthreads();

    float* pr = part + ((size_t)b * NCHUNK + q) * PSTRIDE;

    int tau0 = threadIdx.x * 8;                      // 0..2040
    int t0 = q * TS;
    int tmax = T_DIM - tau0;
    if (tmax > t0 + TS) tmax = t0 + TS;

    float acc[8] = {0.f, 0.f, 0.f, 0.f, 0.f, 0.f, 0.f, 0.f};
    if (t0 < tmax) {
        float w[16];
        {
            int l0 = t0 + tau0;                      // multiple of 8
            float4 w0 = *(const float4*)&ls[SW(l0)];
            float4 w1 = *(const float4*)&ls[SW(l0 + 4)];
            w[0] = w0.x; w[1] = w0.y; w[2] = w0.z; w[3] = w0.w;
            w[4] = w1.x; w[5] = w1.y; w[6] = w1.z; w[7] = w1.w;
        }
        // (tmax - t0) is a multiple of 8: tau0%8==0, TS%8==0
        for (int t = t0; t + 8 <= tmax; t += 8) {
            int ln = t + tau0 + 8;                   // multiple of 8
            float4 n0 = *(const float4*)&ls[SW(ln)];
            float4 n1 = *(const float4*)&ls[SW(ln + 4)];
            w[8] = n0.x;  w[9] = n0.y;  w[10] = n0.z; w[11] = n0.w;
            w[12] = n1.x; w[13] = n1.y; w[14] = n1.z; w[15] = n1.w;
            float4 a0 = *(const float4*)&ls[SW(t)];      // wave-uniform -> broadcast
            float4 a1 = *(const float4*)&ls[SW(t + 4)];
            float as[8] = {a0.x, a0.y, a0.z, a0.w, a1.x, a1.y, a1.z, a1.w};
            #pragma unroll
            for (int s2 = 0; s2 < 8; ++s2) {
                #pragma unroll
                for (int u = 0; u < 8; ++u)
                    acc[u] = fmaf(as[s2], w[s2 + u], acc[u]);
            }
            #pragma unroll
            for (int k = 0; k < 8; ++k) w[k] = w[k + 8];
        }
    }
    // coalesced private store (always: zeros where no work)
    *(float4*)&pr[tau0]     = make_float4(acc[0], acc[1], acc[2], acc[3]);
    *(float4*)&pr[tau0 + 4] = make_float4(acc[4], acc[5], acc[6], acc[7]);

    // lag 2048: wave 3 (tids 192..255) strided over this chunk's t-range
    if (threadIdx.x >= 192) {
        float a2 = 0.f;
        if (t0 < 2048) {
            int tend = t0 + TS;
            if (tend > 2048) tend = 2048;
            for (int t = t0 + (threadIdx.x - 192); t < tend; t += 64)
                a2 += ls[SW(t)] * ls[SW(t + 2048)];
        }
        for (int off = 32; off; off >>= 1) a2 += __shfl_down(a2, off, 64);
        if (threadIdx.x == 192) pr[2048] = a2;
    }
}

// ---------------- K2b: r[b,tau] = sum_q part[b][q][tau] (float4) ----------------
__global__ __launch_bounds__(256) void kreduce(const float* __restrict__ part,
                                               float* __restrict__ r) {
    int b = blockIdx.x;
    const float* pb = part + (size_t)b * NCHUNK * PSTRIDE;
    for (int idx = threadIdx.x; idx < 512; idx += 256) {   // 512 float4 = tau 0..2047
        float4 acc = make_float4(0.f, 0.f, 0.f, 0.f);
        #pragma unroll
        for (int q = 0; q < NCHUNK; ++q) {
            float4 v = *(const float4*)&pb[(size_t)q * PSTRIDE + idx * 4];
            acc.x += v.x; acc.y += v.y; acc.z += v.z; acc.w += v.w;
        }
        *(float4*)&r[(size_t)b * NLAG + idx * 4] = acc;
    }
    if (threadIdx.x == 0) {                          // tau = 2048
        float acc = 0.f;
        #pragma unroll
        for (int q = 0; q < NCHUNK; ++q)
            acc += pb[(size_t)q * PSTRIDE + 2048];
        r[(size_t)b * NLAG + 2048] = acc;
    }
}

// ---------------- K3: LDS-staged DFT, 16 m's per block ----------------
// grid (32,16); block (b,g): m = g*16 + (tid>>4); 16 lanes per m over j-slices.
__global__ __launch_bounds__(256) void kdft(const float* __restrict__ r,
                                            float* __restrict__ out) {
    __shared__ float lr[NLAG];
    int b = blockIdx.x;
    const float* rb = r + (size_t)b * NLAG;
    for (int i = threadIdx.x; i < NLAG; i += 256)
        lr[i] = rb[i];
    __syncthreads();

    int m = blockIdx.y * 16 + (threadIdx.x >> 4);
    int slice = threadIdx.x & 15;
    float part = 0.0f;
    #pragma unroll 8
    for (int k = 0; k < 128; ++k) {                  // j = slice + 16k in 0..2047
        int j = slice + (k << 4);
        int p = (m * j) & 4095;                      // exact integer phase
        part = fmaf(lr[j], __cosf((float)p * THETA), part);
    }
    #pragma unroll
    for (int off = 8; off; off >>= 1) part += __shfl_down(part, off, 16);
    if (slice == 0) {
        // part = sum_{j=0}^{2047} r[j]cos; A = 2*part - r[0] + (-1)^m r[2048]
        float A = 2.0f * part - lr[0] + ((m & 1) ? -lr[2048] : lr[2048]);
        int qp = (2047 * m) & 4095;
        float ang = (float)qp * THETA;
        float g = A * (1.0f / 16384.0f);             // 1/(256 pairs)/sqrt(4096)
        out[(size_t)b * 256 + m] = g * __cosf(ang);
        out[8192 + (size_t)b * 256 + m] = -g * __sinf(ang);
    }
}

extern "C" void kernel_launch(void* const* d_in, const int* in_sizes, int n_in,
                              void* d_out, int out_size, void* d_ws, size_t ws_size,
                              hipStream_t stream) {
    const float* x = (const float*)d_in[0];
    float* out = (float*)d_out;
    float* s = (float*)d_ws;                          // 32*4096 floats (512 KB)
    float* r = s + B_DIM * T_DIM;                     // 32*2049 floats (262 KB)
    float* part = r + B_DIM * NLAG;                   // 32*16*2052 floats (4.2 MB)
    ksum<<<dim3(512), dim3(256), 0, stream>>>(x, s);
    kautoc<<<dim3(B_DIM, NCHUNK), dim3(256), 0, stream>>>(s, part);
    kreduce<<<dim3(B_DIM), dim3(256), 0, stream>>>(part, r);
    kdft<<<dim3(B_DIM, 16), dim3(256), 0, stream>>>(r, out);
}

// Round 7
// 79.115 us; speedup vs baseline: 1.5612x; 1.0627x over previous
//
#include <hip/hip_runtime.h>
#include <hip/hip_bf16.h>

// B=32, T=4096, F=16, L=2047, n=8192, 256 output freqs.
// Math: s[b,t] = sum_f x[b,t,f]; r[b,tau] = sum_t s[t]*s[t+tau] (tau=0..2048)
// G[b,m] = (A[m]/16384) * exp(-2*pi*i*2047*m/4096),
// A[m] = r[0] + 2*sum_{j=1}^{2047} r[j]*cos(2*pi*m*j/4096) + (-1)^m r[2048].
// Output layout (verified R3): PLANAR — Re at [b*256+m], Im at [8192+b*256+m].
// R7: kautoc balanced (uniform work on zero-extended 2304-float local window,
//     no clip branches); kreduce fused into kdft (3 kernels total).

#define B_DIM 32
#define T_DIM 4096
#define NLAG 2049
#define NCHUNK 16
#define TS (T_DIM / NCHUNK)            // 256
#define LOGI 2304                      // staged window: (TS-8)+2040+15 = 2303 max
#define PSTRIDE 2052                   // partial row stride (16B-aligned)
#define THETA 1.5339807878856412e-03f  // 2*pi/4096

// LDS swizzle: +4 floats pad every 32. Preserves 16B alignment/contiguity for
// l%4==0 accesses; makes the stride-8-floats/lane window reads 2-way (free)
// instead of 8-way banked.
#define SW(l) ((l) + (((l) >> 5) << 2))
#define LS_PHYS 2592                   // SW(2303)=2587

// ---------------- K1: s[b,t] = sum_f x[b,t,f] ----------------
__global__ __launch_bounds__(256) void ksum(const float* __restrict__ x,
                                            float* __restrict__ s) {
    int i = blockIdx.x * 256 + threadIdx.x;          // 0..131071 = b*4096+t
    const float4* xv = (const float4*)(x + (size_t)i * 16);
    float4 a = xv[0], b = xv[1], c = xv[2], d = xv[3];
    s[i] = ((a.x + a.y) + (a.z + a.w)) + ((b.x + b.y) + (b.z + b.w)) +
           ((c.x + c.y) + (c.z + c.w)) + ((d.x + d.y) + (d.z + d.w));
}

// ---------------- K2: balanced register-tiled autocorr ----------------
// grid (32, NCHUNK); block (b,q) stages s[t0 .. t0+2304) zero-extended.
// Every thread runs the SAME 32 branch-free iterations (8 t's x 8 lags);
// out-of-range products hit staged zeros and contribute nothing.
__global__ __launch_bounds__(256) void kautoc(const float* __restrict__ s,
                                              float* __restrict__ part) {
    __shared__ __align__(16) float ls[LS_PHYS];
    int b = blockIdx.x;
    int q = blockIdx.y;
    int t0 = q * TS;
    const float* sb = s + (size_t)b * T_DIM;
    for (int idx = threadIdx.x; idx < LOGI / 4; idx += 256) {
        int l = idx * 4;
        int g = t0 + l;                              // 4-aligned
        float4 v = make_float4(0.f, 0.f, 0.f, 0.f);
        if (g < T_DIM) v = *(const float4*)&sb[g];
        *(float4*)&ls[SW(l)] = v;                    // zero-extended tail
    }
    __syncthreads();

    float* pr = part + ((size_t)b * NCHUNK + q) * PSTRIDE;
    int tau0 = threadIdx.x * 8;                      // 0..2040

    float acc[8] = {0.f, 0.f, 0.f, 0.f, 0.f, 0.f, 0.f, 0.f};
    float w[16];
    {
        float4 w0 = *(const float4*)&ls[SW(tau0)];
        float4 w1 = *(const float4*)&ls[SW(tau0 + 4)];
        w[0] = w0.x; w[1] = w0.y; w[2] = w0.z; w[3] = w0.w;
        w[4] = w1.x; w[5] = w1.y; w[6] = w1.z; w[7] = w1.w;
    }
    #pragma unroll 4
    for (int t = 0; t < TS; t += 8) {                // 32 uniform iterations
        int ln = t + tau0 + 8;
        float4 n0 = *(const float4*)&ls[SW(ln)];
        float4 n1 = *(const float4*)&ls[SW(ln + 4)];
        w[8] = n0.x;  w[9] = n0.y;  w[10] = n0.z; w[11] = n0.w;
        w[12] = n1.x; w[13] = n1.y; w[14] = n1.z; w[15] = n1.w;
        float4 a0 = *(const float4*)&ls[SW(t)];      // wave-uniform -> broadcast
        float4 a1 = *(const float4*)&ls[SW(t + 4)];
        float as[8] = {a0.x, a0.y, a0.z, a0.w, a1.x, a1.y, a1.z, a1.w};
        #pragma unroll
        for (int s2 = 0; s2 < 8; ++s2) {
            #pragma unroll
            for (int u = 0; u < 8; ++u)
                acc[u] = fmaf(as[s2], w[s2 + u], acc[u]);
        }
        #pragma unroll
        for (int k = 0; k < 8; ++k) w[k] = w[k + 8];
    }
    *(float4*)&pr[tau0]     = make_float4(acc[0], acc[1], acc[2], acc[3]);
    *(float4*)&pr[tau0 + 4] = make_float4(acc[4], acc[5], acc[6], acc[7]);

    // lag 2048: wave 3, branch-free over staged (zero-extended) window
    if (threadIdx.x >= 192) {
        int sl = threadIdx.x - 192;
        float a2 = 0.f;
        #pragma unroll
        for (int t = 0; t < TS; t += 64)
            a2 += ls[SW(t + sl)] * ls[SW(t + sl + 2048)];
        for (int off = 32; off; off >>= 1) a2 += __shfl_down(a2, off, 64);
        if (threadIdx.x == 192) pr[2048] = a2;
    }
}

// ---------------- K3: fused partial-reduce + LDS-staged DFT ----------------
// grid (32,8); block (b,g): lr[tau] = sum_q part[b][q][tau], then 32 m's
// per block (8 lanes per m over j-slices).
__global__ __launch_bounds__(256) void kdft(const float* __restrict__ part,
                                            float* __restrict__ out) {
    __shared__ float lr[NLAG];
    int b = blockIdx.x;
    const float* pb = part + (size_t)b * NCHUNK * PSTRIDE;
    for (int idx = threadIdx.x; idx < 512; idx += 256) {   // tau 0..2047 as float4
        float4 acc = make_float4(0.f, 0.f, 0.f, 0.f);
        #pragma unroll
        for (int q = 0; q < NCHUNK; ++q) {
            float4 v = *(const float4*)&pb[(size_t)q * PSTRIDE + idx * 4];
            acc.x += v.x; acc.y += v.y; acc.z += v.z; acc.w += v.w;
        }
        *(float4*)&lr[idx * 4] = acc;
    }
    if (threadIdx.x == 0) {                          // tau = 2048
        float acc = 0.f;
        #pragma unroll
        for (int q = 0; q < NCHUNK; ++q)
            acc += pb[(size_t)q * PSTRIDE + 2048];
        lr[2048] = acc;
    }
    __syncthreads();

    int m = blockIdx.y * 32 + (threadIdx.x >> 3);
    int slice = threadIdx.x & 7;
    float partsum = 0.0f;
    #pragma unroll 8
    for (int k = 0; k < 256; ++k) {                  // j = slice + 8k in 0..2047
        int j = slice + (k << 3);
        int p = (m * j) & 4095;                      // exact integer phase
        partsum = fmaf(lr[j], __cosf((float)p * THETA), partsum);
    }
    #pragma unroll
    for (int off = 4; off; off >>= 1) partsum += __shfl_down(partsum, off, 8);
    if (slice == 0) {
        // partsum = sum_{j=0}^{2047} r[j]cos; A = 2*partsum - r[0] + (-1)^m r[2048]
        float A = 2.0f * partsum - lr[0] + ((m & 1) ? -lr[2048] : lr[2048]);
        int qp = (2047 * m) & 4095;
        float ang = (float)qp * THETA;
        float g = A * (1.0f / 16384.0f);             // 1/(256 pairs)/sqrt(4096)
        out[(size_t)b * 256 + m] = g * __cosf(ang);
        out[8192 + (size_t)b * 256 + m] = -g * __sinf(ang);
    }
}

extern "C" void kernel_launch(void* const* d_in, const int* in_sizes, int n_in,
                              void* d_out, int out_size, void* d_ws, size_t ws_size,
                              hipStream_t stream) {
    const float* x = (const float*)d_in[0];
    float* out = (float*)d_out;
    float* s = (float*)d_ws;                          // 32*4096 floats (512 KB)
    float* part = s + B_DIM * T_DIM;                  // 32*16*2052 floats (4.2 MB)
    ksum<<<dim3(512), dim3(256), 0, stream>>>(x, s);
    kautoc<<<dim3(B_DIM, NCHUNK), dim3(256), 0, stream>>>(s, part);
    kdft<<<dim3(B_DIM, 8), dim3(256), 0, stream>>>(part, out);
}